// Round 1
// baseline (97.543 us; speedup 1.0000x reference)
//
#include <hip/hip_runtime.h>
#include <hip/hip_bf16.h>
#include <math.h>

#define N 256
#define D 512
#define C 16
#define NBINS 1000
#define EPSF 1e-9f
#define RPB 4
#define CHUNK 512

__device__ inline float waveReduceSum(float v) {
#pragma unroll
    for (int off = 32; off > 0; off >>= 1) v += __shfl_down(v, off, 64);
    return v;
}
__device__ inline double waveReduceSumD(double v) {
#pragma unroll
    for (int off = 32; off > 0; off >>= 1) v += __shfl_down(v, off, 64);
    return v;
}

// lab[i] = argmax_c labels[i,c] (first max, matching jnp.argmax)
__global__ void k_argmax(const float* __restrict__ labels, int* __restrict__ lab) {
    int i = blockIdx.x * blockDim.x + threadIdx.x;
    if (i >= N) return;
    float best = labels[i * C];
    int bi = 0;
#pragma unroll
    for (int c = 1; c < C; ++c) {
        float v = labels[i * C + c];
        if (v > best) { best = v; bi = c; }
    }
    lab[i] = bi;
}

// L2-normalize rows of T and S; write row-major xn and transposed xnT
__global__ void k_norm(const float* __restrict__ T, const float* __restrict__ S,
                       float* __restrict__ xn, float* __restrict__ xnT) {
    int i = blockIdx.x;
    int mat = blockIdx.y;
    const float* in = mat ? S : T;
    int tid = threadIdx.x;  // 256 threads, row has 512 elems
    float v0 = in[i * D + tid];
    float v1 = in[i * D + 256 + tid];
    float ss = v0 * v0 + v1 * v1;
    ss = waveReduceSum(ss);
    __shared__ float lds[4];
    __shared__ float inv_s;
    int wid = tid >> 6, lane = tid & 63;
    if (lane == 0) lds[wid] = ss;
    __syncthreads();
    if (tid == 0) {
        float tot = lds[0] + lds[1] + lds[2] + lds[3];
        inv_s = 1.0f / fmaxf(sqrtf(tot), 1e-12f);
    }
    __syncthreads();
    float inv = inv_s;
    float* xnm = xn + mat * (N * D);
    float* xnTm = xnT + mat * (N * D);
    float a = v0 * inv, b = v1 * inv;
    xnm[i * D + tid] = a;
    xnm[i * D + 256 + tid] = b;
    xnTm[tid * N + i] = a;
    xnTm[(tid + 256) * N + i] = b;
}

// cos = xn @ xn^T ; block computes RPB rows x 256 cols
__global__ void k_cos(const float* __restrict__ xn, const float* __restrict__ xnT,
                      float* __restrict__ cosm) {
    int mat = blockIdx.y;
    int i0 = blockIdx.x * RPB;
    int j = threadIdx.x;  // 256
    const float* xnm = xn + mat * (N * D);
    const float* xnTm = xnT + mat * (N * D);
    __shared__ float rows[RPB][D];
#pragma unroll
    for (int r = 0; r < RPB; ++r) {
        rows[r][j] = xnm[(i0 + r) * D + j];
        rows[r][j + 256] = xnm[(i0 + r) * D + 256 + j];
    }
    __syncthreads();
    float acc[RPB] = {0.f, 0.f, 0.f, 0.f};
    for (int k = 0; k < D; ++k) {
        float xb = xnTm[k * N + j];  // coalesced
#pragma unroll
        for (int r = 0; r < RPB; ++r) acc[r] += rows[r][k] * xb;
    }
    float* cm = cosm + mat * (N * N);
#pragma unroll
    for (int r = 0; r < RPB; ++r) cm[(i0 + r) * N + j] = acc[r];
}

// per-row pos/neg means of cos; also total pos/neg pair counts (mat 0 only)
__global__ void k_E(const float* __restrict__ cosm, const int* __restrict__ lab,
                    float* __restrict__ Earr, float* __restrict__ cnts) {
    int i = blockIdx.x, mat = blockIdx.y;
    int j = threadIdx.x;  // 256
    float c = cosm[mat * (N * N) + i * N + j];
    bool same = (lab[i] == lab[j]);
    bool pos = same && (i != j);
    bool neg = !same;
    float ps = pos ? c : 0.f, ns = neg ? c : 0.f;
    float pc = pos ? 1.f : 0.f, nc = neg ? 1.f : 0.f;
    ps = waveReduceSum(ps);
    ns = waveReduceSum(ns);
    pc = waveReduceSum(pc);
    nc = waveReduceSum(nc);
    __shared__ float lds[4][4];
    int wid = j >> 6, lane = j & 63;
    if (lane == 0) { lds[wid][0] = ps; lds[wid][1] = ns; lds[wid][2] = pc; lds[wid][3] = nc; }
    __syncthreads();
    if (j == 0) {
        float tps = 0, tns = 0, tpc = 0, tnc = 0;
        for (int w = 0; w < 4; ++w) {
            tps += lds[w][0]; tns += lds[w][1]; tpc += lds[w][2]; tnc += lds[w][3];
        }
        Earr[(mat * 2 + 0) * N + i] = tps / tpc;
        Earr[(mat * 2 + 1) * N + i] = tns / tnc;
        if (mat == 0) { atomicAdd(&cnts[0], tpc); atomicAdd(&cnts[1], tnc); }
    }
}

// Gaussian soft histogram: thread = bin, block processes CHUNK dists from LDS
__global__ void __launch_bounds__(1024) k_hist(const float* __restrict__ cosm,
                                               const int* __restrict__ lab,
                                               float* __restrict__ hist) {
    int mat = blockIdx.y;
    int base = blockIdx.x * CHUNK;
    int tid = threadIdx.x;
    __shared__ float2 sf[CHUNK];
    if (tid < CHUNK) {
        int idx = base + tid;
        int i = idx >> 8, j = idx & 255;
        float d = cosm[mat * (N * N) + idx];
        float f = (lab[i] == lab[j]) ? ((i == j) ? 0.f : 1.f) : -1.f;
        sf[tid] = make_float2(d, f);
    }
    __syncthreads();
    if (tid >= NBINS) return;
    float tb = -1.0f + 0.002f * (float)tid;
    float pa = 0.f, na = 0.f;
    for (int s = 0; s < CHUNK; ++s) {
        float2 df = sf[s];                  // wave-uniform LDS broadcast
        float q = df.x - tb;
        float e = __expf(-50.0f * q * q);   // exp(-0.5*((d-t)/0.1)^2)
        pa += e * fmaxf(df.y, 0.f);
        na += e * fmaxf(-df.y, 0.f);
    }
    atomicAdd(&hist[(mat * 2 + 0) * NBINS + tid], pa);
    atomicAdd(&hist[(mat * 2 + 1) * NBINS + tid], na);
}

// final: KLs over bins + order terms over rows, double accumulation
__global__ void __launch_bounds__(1024) k_final(const float* __restrict__ hist,
                                                const float* __restrict__ Earr,
                                                const float* __restrict__ cnts,
                                                float* __restrict__ out) {
    int tid = threadIdx.x;
    double poskl = 0, negkl = 0, o1 = 0, o2 = 0, o3 = 0;
    float pcnt = cnts[0], ncnt = cnts[1];
    if (tid < NBINS) {
        float pt = hist[0 * NBINS + tid] / pcnt;
        float nt = hist[1 * NBINS + tid] / ncnt;
        float ps = hist[2 * NBINS + tid] / pcnt;
        float ns = hist[3 * NBINS + tid] / ncnt;
        poskl = (double)((pt + EPSF) * (logf(pt + EPSF) - logf(ps + EPSF)));
        negkl = (double)((nt + EPSF) * (logf(nt + EPSF) - logf(ns + EPSF)));
    }
    if (tid < N) {
        float ept = Earr[0 * N + tid];
        float ent = Earr[1 * N + tid];
        float eps_ = Earr[2 * N + tid];
        float ens = Earr[3 * N + tid];
        o1 = fabs((double)(ept - eps_));
        o2 = fabs((double)(ent - ens));
        o3 = (double)eps_ - (double)ens;
    }
    poskl = waveReduceSumD(poskl);
    negkl = waveReduceSumD(negkl);
    o1 = waveReduceSumD(o1);
    o2 = waveReduceSumD(o2);
    o3 = waveReduceSumD(o3);
    __shared__ double lds[16][5];
    int wid = tid >> 6, lane = tid & 63;
    if (lane == 0) {
        lds[wid][0] = poskl; lds[wid][1] = negkl;
        lds[wid][2] = o1; lds[wid][3] = o2; lds[wid][4] = o3;
    }
    __syncthreads();
    if (tid == 0) {
        double a = 0, b = 0, c = 0, d = 0, e = 0;
        for (int w = 0; w < 16; ++w) {
            a += lds[w][0]; b += lds[w][1]; c += lds[w][2]; d += lds[w][3]; e += lds[w][4];
        }
        double loss = 0.1 * a + 0.02 * b + 0.5 * ((c + d + e) / (double)N);
        out[0] = (float)loss;
    }
}

extern "C" void kernel_launch(void* const* d_in, const int* in_sizes, int n_in,
                              void* d_out, int out_size, void* d_ws, size_t ws_size,
                              hipStream_t stream) {
    const float* T = (const float*)d_in[0];
    const float* S = (const float*)d_in[1];
    const float* labels = (const float*)d_in[2];
    float* out = (float*)d_out;

    float* ws = (float*)d_ws;
    float* xn = ws;                   // 2*N*D
    float* xnT = xn + 2 * N * D;      // 2*N*D
    float* cosm = xnT + 2 * N * D;    // 2*N*N
    float* hist = cosm + 2 * N * N;   // 4*NBINS
    float* Earr = hist + 4 * NBINS;   // 4*N
    float* cnts = Earr + 4 * N;       // 2
    int* lab = (int*)(cnts + 2);      // N ints

    // zero atomically-accumulated regions (hist + Earr + cnts)
    hipMemsetAsync(hist, 0, (size_t)(4 * NBINS + 4 * N + 2) * sizeof(float), stream);

    k_argmax<<<1, 256, 0, stream>>>(labels, lab);
    k_norm<<<dim3(N, 2), 256, 0, stream>>>(T, S, xn, xnT);
    k_cos<<<dim3(N / RPB, 2), 256, 0, stream>>>(xn, xnT, cosm);
    k_E<<<dim3(N, 2), 256, 0, stream>>>(cosm, lab, Earr, cnts);
    k_hist<<<dim3(N * N / CHUNK, 2), 1024, 0, stream>>>(cosm, lab, hist);
    k_final<<<1, 1024, 0, stream>>>(hist, Earr, cnts, out);
}

// Round 2
// 81.591 us; speedup vs baseline: 1.1955x; 1.1955x over previous
//
#include <hip/hip_runtime.h>
#include <hip/hip_bf16.h>
#include <math.h>

#define N 256
#define D 512
#define C 16
#define NBINS 1000
#define EPSF 1e-9f
#define CHUNK 256
// -50/ln(2): exp(-50*q^2) = exp2(KEXP2*q^2)
#define KEXP2 -72.134752f
// exp2(KEXP2*q2) < 2.1e-9 beyond this; contributes < 2e-9 per bin prob
#define Q2CUT 20.0f

__device__ inline float waveReduceSum(float v) {
#pragma unroll
    for (int off = 32; off > 0; off >>= 1) v += __shfl_down(v, off, 64);
    return v;
}
__device__ inline double waveReduceSumD(double v) {
#pragma unroll
    for (int off = 32; off > 0; off >>= 1) v += __shfl_down(v, off, 64);
    return v;
}

// L2-normalize rows of T and S -> xn (row major) and xnT (transposed).
// Fused: lab[i] = argmax_c labels[i,c] (first-max), done by lane 0 of mat 0 blocks.
__global__ void k_norm(const float* __restrict__ T, const float* __restrict__ S,
                       const float* __restrict__ labels,
                       float* __restrict__ xn, float* __restrict__ xnT,
                       int* __restrict__ lab) {
    int i = blockIdx.x;
    int mat = blockIdx.y;
    const float* in = mat ? S : T;
    int tid = threadIdx.x;  // 256 threads, row has 512 elems
    if (mat == 0 && tid == 0) {
        float best = labels[i * C];
        int bi = 0;
#pragma unroll
        for (int c = 1; c < C; ++c) {
            float v = labels[i * C + c];
            if (v > best) { best = v; bi = c; }
        }
        lab[i] = bi;
    }
    float v0 = in[i * D + tid];
    float v1 = in[i * D + 256 + tid];
    float ss = v0 * v0 + v1 * v1;
    ss = waveReduceSum(ss);
    __shared__ float lds[4];
    __shared__ float inv_s;
    int wid = tid >> 6, lane = tid & 63;
    if (lane == 0) lds[wid] = ss;
    __syncthreads();
    if (tid == 0) {
        float tot = lds[0] + lds[1] + lds[2] + lds[3];
        inv_s = 1.0f / fmaxf(sqrtf(tot), 1e-12f);
    }
    __syncthreads();
    float inv = inv_s;
    float* xnm = xn + mat * (N * D);
    float* xnTm = xnT + mat * (N * D);
    float a = v0 * inv, b = v1 * inv;
    xnm[i * D + tid] = a;
    xnm[i * D + 256 + tid] = b;
    xnTm[tid * N + i] = a;
    xnTm[(tid + 256) * N + i] = b;
}

// Fused cos + classify + per-row E means + pack (d, wp) pairs.
// Block = (2 rows, mat); 256 threads = col j.
__global__ void __launch_bounds__(256) k_cos(
        const float* __restrict__ xn, const float* __restrict__ xnT,
        const int* __restrict__ lab,
        float2* __restrict__ c2, float* __restrict__ Earr,
        float* __restrict__ cpos) {
    int mat = blockIdx.y;
    int i0 = blockIdx.x * 2;
    int j = threadIdx.x;  // 256
    const float* xnm = xn + mat * (N * D);
    const float* xc = xnT + mat * (N * D);
    __shared__ float2 rows2[D];  // (row_i0[k], row_i0+1[k])
    {
        float r0a = xnm[i0 * D + j];
        float r0b = xnm[i0 * D + 256 + j];
        float r1a = xnm[(i0 + 1) * D + j];
        float r1b = xnm[(i0 + 1) * D + 256 + j];
        rows2[j] = make_float2(r0a, r1a);
        rows2[j + 256] = make_float2(r0b, r1b);
    }
    int labj = lab[j];
    int li0 = lab[i0], li1 = lab[i0 + 1];
    __syncthreads();

    float a0 = 0.f, a1 = 0.f, a2 = 0.f, a3 = 0.f;  // 2 chains per row
#pragma unroll 8
    for (int k = 0; k < D; ++k) {
        float xb = xc[k * N + j];  // coalesced
        float2 r = rows2[k];       // wave-uniform broadcast
        if (k & 1) { a1 = fmaf(r.x, xb, a1); a3 = fmaf(r.y, xb, a3); }
        else       { a0 = fmaf(r.x, xb, a0); a2 = fmaf(r.y, xb, a2); }
    }
    float d0 = a0 + a1;
    float d1 = a2 + a3;

    float wp0 = (labj == li0 && j != i0) ? 1.f : 0.f;
    float wp1 = (labj == li1 && j != (i0 + 1)) ? 1.f : 0.f;
    float2* cm = c2 + mat * (N * N);
    cm[i0 * N + j] = make_float2((j == i0) ? 9.0f : d0, wp0);
    cm[(i0 + 1) * N + j] = make_float2((j == i0 + 1) ? 9.0f : d1, wp1);

    // reductions: per row {sum_all(j!=i), sum_pos, cnt_pos}
    float sA0 = (j != i0) ? d0 : 0.f;
    float sA1 = (j != i0 + 1) ? d1 : 0.f;
    float sP0 = d0 * wp0, sP1 = d1 * wp1;
    float v0 = waveReduceSum(sA0);
    float v1 = waveReduceSum(sP0);
    float v2 = waveReduceSum(wp0);
    float v3 = waveReduceSum(sA1);
    float v4 = waveReduceSum(sP1);
    float v5 = waveReduceSum(wp1);
    __shared__ float red[4][6];
    int wid = j >> 6, lane = j & 63;
    if (lane == 0) {
        red[wid][0] = v0; red[wid][1] = v1; red[wid][2] = v2;
        red[wid][3] = v3; red[wid][4] = v4; red[wid][5] = v5;
    }
    __syncthreads();
    if (j == 0) {
        float t[6] = {0, 0, 0, 0, 0, 0};
        for (int w = 0; w < 4; ++w)
            for (int q = 0; q < 6; ++q) t[q] += red[w][q];
        // row i0
        float pc0 = t[2], nc0 = 255.f - t[2];
        Earr[(mat * 2 + 0) * N + i0] = t[1] / pc0;
        Earr[(mat * 2 + 1) * N + i0] = (t[0] - t[1]) / nc0;
        // row i0+1
        float pc1 = t[5], nc1 = 255.f - t[5];
        Earr[(mat * 2 + 0) * N + i0 + 1] = t[4] / pc1;
        Earr[(mat * 2 + 1) * N + i0 + 1] = (t[3] - t[4]) / nc1;
        if (mat == 0) { cpos[i0] = pc0; cpos[i0 + 1] = pc1; }
    }
}

// Gaussian soft histogram: thread = bin; block stages CHUNK (d,wp) pairs in LDS.
// sa = sum over all non-diag pairs, pa = sum over pos pairs; neg = sa - pa later.
__global__ void __launch_bounds__(1024, 8) k_hist(const float2* __restrict__ c2,
                                                  float* __restrict__ hp,
                                                  float* __restrict__ hs) {
    int mat = blockIdx.y;
    int base = blockIdx.x * CHUNK;
    int tid = threadIdx.x;
    __shared__ float2 sf[CHUNK];
    if (tid < CHUNK) sf[tid] = c2[mat * (N * N) + base + tid];
    __syncthreads();
    float tb = -1.0f + 0.002f * (float)tid;  // bins; tid>=1000 harmless (never hits)
    float pa = 0.f, sa = 0.f;
    for (int s = 0; s < CHUNK; s += 4) {
#pragma unroll
        for (int u = 0; u < 4; ++u) {
            float2 v = sf[s + u];            // wave-uniform LDS broadcast
            float q = v.x - tb;
            float q2 = q * q;
            if (q2 < Q2CUT) {                // wave-coherent (adjacent bins)
                float e = __builtin_amdgcn_exp2f(KEXP2 * q2);
                sa += e;
                pa = fmaf(e, v.y, pa);
            }
        }
    }
    if (tid < NBINS) {
        atomicAdd(&hp[mat * NBINS + tid], pa);
        atomicAdd(&hs[mat * NBINS + tid], sa);
    }
}

// final: counts from cpos, KLs over bins + order terms over rows (double accum)
__global__ void __launch_bounds__(1024) k_final(const float* __restrict__ hp,
                                                const float* __restrict__ hs,
                                                const float* __restrict__ Earr,
                                                const float* __restrict__ cpos,
                                                float* __restrict__ out) {
    int tid = threadIdx.x;
    int wid = tid >> 6, lane = tid & 63;
    // phase 1: total pos count
    __shared__ float cred[16];
    __shared__ float pcnt_s;
    float cv = (tid < N) ? cpos[tid] : 0.f;
    cv = waveReduceSum(cv);
    if (lane == 0) cred[wid] = cv;
    __syncthreads();
    if (tid == 0) {
        float t = 0;
        for (int w = 0; w < 16; ++w) t += cred[w];
        pcnt_s = t;
    }
    __syncthreads();
    float pcnt = pcnt_s;
    float ncnt = 65280.f - pcnt;  // N*N - N - pcnt

    double poskl = 0, negkl = 0, o1 = 0, o2 = 0, o3 = 0;
    if (tid < NBINS) {
        float hpT = hp[0 * NBINS + tid], hsT = hs[0 * NBINS + tid];
        float hpS = hp[1 * NBINS + tid], hsS = hs[1 * NBINS + tid];
        float pt = hpT / pcnt;
        float nt = (hsT - hpT) / ncnt;
        float ps = hpS / pcnt;
        float ns = (hsS - hpS) / ncnt;
        poskl = (double)((pt + EPSF) * (logf(pt + EPSF) - logf(ps + EPSF)));
        negkl = (double)((nt + EPSF) * (logf(nt + EPSF) - logf(ns + EPSF)));
    }
    if (tid < N) {
        float ept = Earr[0 * N + tid];
        float ent = Earr[1 * N + tid];
        float eps_ = Earr[2 * N + tid];
        float ens = Earr[3 * N + tid];
        o1 = fabs((double)ept - (double)eps_);
        o2 = fabs((double)ent - (double)ens);
        o3 = (double)eps_ - (double)ens;
    }
    poskl = waveReduceSumD(poskl);
    negkl = waveReduceSumD(negkl);
    o1 = waveReduceSumD(o1);
    o2 = waveReduceSumD(o2);
    o3 = waveReduceSumD(o3);
    __shared__ double lds[16][5];
    if (lane == 0) {
        lds[wid][0] = poskl; lds[wid][1] = negkl;
        lds[wid][2] = o1; lds[wid][3] = o2; lds[wid][4] = o3;
    }
    __syncthreads();
    if (tid == 0) {
        double a = 0, b = 0, c = 0, d = 0, e = 0;
        for (int w = 0; w < 16; ++w) {
            a += lds[w][0]; b += lds[w][1]; c += lds[w][2]; d += lds[w][3]; e += lds[w][4];
        }
        double loss = 0.1 * a + 0.02 * b + 0.5 * ((c + d + e) / (double)N);
        out[0] = (float)loss;
    }
}

extern "C" void kernel_launch(void* const* d_in, const int* in_sizes, int n_in,
                              void* d_out, int out_size, void* d_ws, size_t ws_size,
                              hipStream_t stream) {
    const float* T = (const float*)d_in[0];
    const float* S = (const float*)d_in[1];
    const float* labels = (const float*)d_in[2];
    float* out = (float*)d_out;

    float* ws = (float*)d_ws;
    float* xn = ws;                       // 2*N*D            = 262144
    float* xnT = xn + 2 * N * D;          // 2*N*D            = 262144
    float2* c2 = (float2*)(xnT + 2 * N * D);  // 2*N*N float2 = 262144 floats
    float* hp = (float*)(c2 + 2 * N * N); // 2*NBINS
    float* hs = hp + 2 * NBINS;           // 2*NBINS
    float* Earr = hs + 2 * NBINS;         // 4*N
    float* cpos = Earr + 4 * N;           // N
    int* lab = (int*)(cpos + N);          // N ints

    // zero only the atomically-accumulated histograms
    hipMemsetAsync(hp, 0, (size_t)(4 * NBINS) * sizeof(float), stream);

    k_norm<<<dim3(N, 2), 256, 0, stream>>>(T, S, labels, xn, xnT, lab);
    k_cos<<<dim3(N / 2, 2), 256, 0, stream>>>(xn, xnT, lab, c2, Earr, cpos);
    k_hist<<<dim3(N * N / CHUNK, 2), 1024, 0, stream>>>(c2, hp, hs);
    k_final<<<1, 1024, 0, stream>>>(hp, hs, Earr, cpos, out);
}